// Round 2
// baseline (495.287 us; speedup 1.0000x reference)
//
#include <hip/hip_runtime.h>
#include <hip/hip_bf16.h>

#define B_ 64
#define T_ 128
#define E_ 256
#define H_ 256
#define OW_ 512   // output row width = 2*H (elements)
#define LP 264    // LDS bf16 row pitch for proj_mfma staging (elements)
#define MAGIC 0x5AD00000u

typedef unsigned short ushort_t;
typedef __attribute__((ext_vector_type(8))) short bf16x8;   // 8 bf16 = 4 VGPRs
typedef __attribute__((ext_vector_type(4))) float f32x4;    // 4 f32 acc

// Workgroup barrier WITHOUT the compiler's vmcnt(0) drain (validated r7/r8).
#define LGKM_BARRIER() asm volatile("s_waitcnt lgkmcnt(0)\n\ts_barrier" ::: "memory")

__device__ __forceinline__ ushort_t f2bf(float f) {
    unsigned int x = __float_as_uint(f);
    unsigned int r = x + 0x7FFFu + ((x >> 16) & 1u);
    return (ushort_t)(r >> 16);
}
__device__ __forceinline__ float fast_tanh(float x) {
    float e = __expf(2.0f * x);
    return 1.0f - 2.0f * __builtin_amdgcn_rcpf(e + 1.0f);
}
__device__ __forceinline__ bf16x8 load_bfrag(const float* W, const float* M,
                                             size_t base) {
    float4 a = *(const float4*)(W + base);
    float4 b = *(const float4*)(W + base + 4);
    if (M) {
        float4 ma = *(const float4*)(M + base);
        float4 mb = *(const float4*)(M + base + 4);
        a.x *= ma.x; a.y *= ma.y; a.z *= ma.z; a.w *= ma.w;
        b.x *= mb.x; b.y *= mb.y; b.z *= mb.z; b.w *= mb.w;
    }
    union { bf16x8 v; ushort_t u[8]; } r;
    r.u[0] = f2bf(a.x); r.u[1] = f2bf(a.y); r.u[2] = f2bf(a.z); r.u[3] = f2bf(a.w);
    r.u[4] = f2bf(b.x); r.u[5] = f2bf(b.y); r.u[6] = f2bf(b.z); r.u[7] = f2bf(b.w);
    return r.v;
}

// Fragment-major LDS A-layout (r9-verified): element (r,k) at
//   off = (k>>5)*512 + ((k>>3)&3)*128 + r*8 + (k&7)
// Reader lane L reads frag kk as ds_read_b128 at element lane*8 + kk*512
// (= row l15, k = kk*32 + quad*8 + j): exact MFMA A-frag, linear in lane.
__device__ __forceinline__ int a_off(int r, int k) {
    return ((k >> 5) << 9) + (((k >> 3) & 3) << 7) + (r << 3) + (k & 7);
}

// ---------------------------------------------------------------------------
// pack_frags: pre-pack B-operand fragments (bf16, frag-major) into workspace.
// pk[(mat*128 + wv*16 + tc*8 + kk)*64 + lane] = frag for
//   n = wv*32 + tc*16 + l15, k = kk*32 + quad*8 + j  (j = 0..7)
// mat 0: W_rec0*mask0 (held), 1: W_in1 (streamed), 2: W_rec1*mask1 (streamed)
// ---------------------------------------------------------------------------
__global__ __launch_bounds__(64, 8)
void pack_frags(const float* __restrict__ Wr0, const float* __restrict__ m0,
                const float* __restrict__ Wi1,
                const float* __restrict__ Wr1, const float* __restrict__ m1,
                bf16x8* __restrict__ pk)
{
    const int mat  = blockIdx.x >> 7;      // 0..2
    const int f    = blockIdx.x & 127;     // wv*16 + tc*8 + kk
    const int lane = threadIdx.x;
    const int wv = f >> 4, tc2 = (f >> 3) & 1, kk = f & 7;
    const int quad = lane >> 4, l15 = lane & 15;
    const int c = wv * 32 + tc2 * 16 + l15;
    const size_t base = (size_t)c * H_ + kk * 32 + quad * 8;
    const float* W = (mat == 0) ? Wr0 : (mat == 1) ? Wi1 : Wr1;
    const float* M = (mat == 0) ? m0  : (mat == 1) ? nullptr : m1;
    pk[(size_t)blockIdx.x * 64 + lane] = load_bfrag(W, M, base);
}

// ---------------------------------------------------------------------------
// ltc_merged (r10): BOTH LTC levels in one WG per batch group. 8 waves x
// TC=2 (512 thr, 2 waves/SIMD -> TLP preserved, <=256 VGPR).
// Per step t (0..T_):
//   rec0 : h0(t)   = F(h0(t-1) @ Wr0', xp0(t))          [Bf0 held in regs]
//   fuse : xp1(t-1)= h0(t-1) @ Wi1' + b1  -> REGISTERS  [Bs streamed, win 1]
//   rec1 : h1(t-1) = G(h1(t-2) @ Wr1', xp1(t-1))        [Bs streamed, win 2]
// xp1 never leaves registers (fuse C-thread == rec1 epilogue thread).
// No xf workspace, no flags, no vmcnt drains: one lgkm barrier per step.
// A-tiles: frag-major LDS; pad-row lanes ((l15&2)!=0) read broadcast addr 0
// (their C rows are discarded) -> ~half LDS bandwidth per tile.
// Alias safety: xp0 row r read at iter r-1 (prefetch) / prologue; h1 write
// to row r cols 256.. happens at iter r+1, same thread -> program order.
// ---------------------------------------------------------------------------
__global__ __launch_bounds__(512, 2)
void ltc_merged(float* out, const bf16x8* __restrict__ pk,
                const float* __restrict__ tau0,
                const float* __restrict__ b1v,
                const float* __restrict__ tau1)
{
    const int tid  = threadIdx.x;
    const int lane = tid & 63;
    const int wv   = tid >> 6;     // 0..7
    const int quad = lane >> 4;
    const int l15  = lane & 15;
    const int n0   = wv * 32;
    const int bg   = blockIdx.x * 8;
    const bool rlane = (l15 & 2) == 0;   // real A-row lanes

    __shared__ __align__(16) ushort_t hb[2][2][4096];   // [level][buf]

    const bf16x8* pk0 = pk + (size_t)(wv * 16) * 64;
    const bf16x8* pk1 = pk + (size_t)(128 + wv * 16) * 64;
    const bf16x8* pk2 = pk + (size_t)(256 + wv * 16) * 64;

    // held weights: level-0 recurrent
    bf16x8 Bf0[2][8];
    #pragma unroll
    for (int tc = 0; tc < 2; ++tc)
        #pragma unroll
        for (int kk = 0; kk < 8; ++kk)
            Bf0[tc][kk] = pk0[(tc * 8 + kk) * 64 + lane];

    float inv_t0[2], inv_t1[2], b2[2], h0p[2][2], h1p[2][2];
    #pragma unroll
    for (int tc = 0; tc < 2; ++tc) {
        const int c = n0 + tc * 16 + l15;
        inv_t0[tc] = 1.0f / (logf(1.0f + __expf(tau0[c])) + 0.1f);
        inv_t1[tc] = 1.0f / (logf(1.0f + __expf(tau1[c])) + 0.1f);
        b2[tc] = b1v[c];
        h0p[tc][0] = h0p[tc][1] = 0.f;
        h1p[tc][0] = h1p[tc][1] = 0.f;
    }

    int woff[2][2];
    #pragma unroll
    for (int tc = 0; tc < 2; ++tc)
        #pragma unroll
        for (int reg = 0; reg < 2; ++reg)
            woff[tc][reg] = a_off(quad * 4 + reg, n0 + tc * 16 + l15);

    // xp0 prologue (row 0); 1-ahead prefetch thereafter
    float xp_c[2][2], xp_n[2][2];
    #pragma unroll
    for (int tc = 0; tc < 2; ++tc)
        #pragma unroll
        for (int reg = 0; reg < 2; ++reg) {
            const int b = bg + quad * 2 + reg;
            xp_c[tc][reg] = out[(size_t)(b * T_) * OW_ + H_ + n0 + tc * 16 + l15];
            xp_n[tc][reg] = 0.f;
        }

    for (int i = tid; i < 2 * 2 * 4096 / 2; i += 512)
        ((unsigned int*)&hb[0][0][0])[i] = 0u;

    const int ab = rlane ? (lane * 8) : 0;   // pad lanes: broadcast addr

    __syncthreads();

    #pragma unroll 1
    for (int t = 0; t <= T_; ++t) {
        const int rb = t & 1;
        bf16x8 Bs[2][8];

        // stream window 1: fuse weights (W_in1) — consumed mid-step
        #pragma unroll
        for (int tc = 0; tc < 2; ++tc)
            #pragma unroll
            for (int kk = 0; kk < 8; ++kk)
                Bs[tc][kk] = pk1[(tc * 8 + kk) * 64 + lane];

        // xp0 prefetch for next step
        if (t + 1 < T_) {
            #pragma unroll
            for (int tc = 0; tc < 2; ++tc)
                #pragma unroll
                for (int reg = 0; reg < 2; ++reg) {
                    const int b = bg + quad * 2 + reg;
                    xp_n[tc][reg] = out[(size_t)(b * T_ + t + 1) * OW_ + H_
                                        + n0 + tc * 16 + l15];
                }
        }

        // A fragments, level 0: h0(t-1)
        bf16x8 Af0[8];
        {
            const ushort_t* a0 = &hb[0][rb][0];
            #pragma unroll
            for (int kk = 0; kk < 8; ++kk)
                Af0[kk] = *(const bf16x8*)(a0 + ab + kk * 512);
        }

        // rec0 (held weights — no stream wait)
        f32x4 acc0[2] = {{0.f,0.f,0.f,0.f},{0.f,0.f,0.f,0.f}};
        if (t < T_) {
            #pragma unroll
            for (int kk = 0; kk < 8; ++kk)
                #pragma unroll
                for (int tc = 0; tc < 2; ++tc)
                    acc0[tc] = __builtin_amdgcn_mfma_f32_16x16x32_bf16(
                        Af0[kk], Bf0[tc][kk], acc0[tc], 0, 0, 0);
        }

        // fuse: xp1(t-1) = h0(t-1) @ Wi1' + b1  (waits stream window 1)
        f32x4 acc2[2];
        if (t > 0) {
            #pragma unroll
            for (int tc = 0; tc < 2; ++tc)
                acc2[tc] = (f32x4){b2[tc], b2[tc], b2[tc], b2[tc]};
            #pragma unroll
            for (int kk = 0; kk < 8; ++kk)
                #pragma unroll
                for (int tc = 0; tc < 2; ++tc)
                    acc2[tc] = __builtin_amdgcn_mfma_f32_16x16x32_bf16(
                        Af0[kk], Bs[tc][kk], acc2[tc], 0, 0, 0);
        }

        // stream window 2: rec1 weights (W_rec1*mask1) — same registers
        #pragma unroll
        for (int tc = 0; tc < 2; ++tc)
            #pragma unroll
            for (int kk = 0; kk < 8; ++kk)
                Bs[tc][kk] = pk2[(tc * 8 + kk) * 64 + lane];

        // A fragments, level 1: h1(t-2)
        bf16x8 Af1[8];
        {
            const ushort_t* a1 = &hb[1][rb][0];
            #pragma unroll
            for (int kk = 0; kk < 8; ++kk)
                Af1[kk] = *(const bf16x8*)(a1 + ab + kk * 512);
        }

        // epilogue 0: h0(t)  (VALU here also covers stream-2 latency)
        if (t < T_) {
            #pragma unroll
            for (int tc = 0; tc < 2; ++tc) {
                const int c = n0 + tc * 16 + l15;
                #pragma unroll
                for (int reg = 0; reg < 2; ++reg) {
                    const int b = bg + quad * 2 + reg;
                    const float pre = xp_c[tc][reg] + acc0[tc][reg];
                    const float hn  = h0p[tc][reg]
                                    + (fast_tanh(pre) - h0p[tc][reg]) * inv_t0[tc];
                    h0p[tc][reg] = hn;
                    hb[0][rb ^ 1][woff[tc][reg]] = f2bf(hn);
                    out[(size_t)(b * T_ + t) * OW_ + c] = hn;
                }
            }
            #pragma unroll
            for (int tc = 0; tc < 2; ++tc)
                #pragma unroll
                for (int reg = 0; reg < 2; ++reg)
                    xp_c[tc][reg] = xp_n[tc][reg];
        }

        // rec1 + epilogue 1: h1(t-1)
        if (t > 0) {
            f32x4 acc1[2] = {{0.f,0.f,0.f,0.f},{0.f,0.f,0.f,0.f}};
            #pragma unroll
            for (int kk = 0; kk < 8; ++kk)
                #pragma unroll
                for (int tc = 0; tc < 2; ++tc)
                    acc1[tc] = __builtin_amdgcn_mfma_f32_16x16x32_bf16(
                        Af1[kk], Bs[tc][kk], acc1[tc], 0, 0, 0);
            #pragma unroll
            for (int tc = 0; tc < 2; ++tc) {
                const int c = n0 + tc * 16 + l15;
                #pragma unroll
                for (int reg = 0; reg < 2; ++reg) {
                    const int b = bg + quad * 2 + reg;
                    const float pre = acc2[tc][reg] + acc1[tc][reg];
                    const float hn  = h1p[tc][reg]
                                    + (fast_tanh(pre) - h1p[tc][reg]) * inv_t1[tc];
                    h1p[tc][reg] = hn;
                    hb[1][rb ^ 1][woff[tc][reg]] = f2bf(hn);
                    out[(size_t)(b * T_ + t - 1) * OW_ + H_ + c] = hn;
                }
            }
        }

        if (t < T_) LGKM_BARRIER();
    }
}

// ---------------------------------------------------------------------------
// Fallback standalone scan (r9-verified structure; only used if workspace
// is too small for the packed fragments — never expected in practice).
// ---------------------------------------------------------------------------
template<bool FUSE, bool WAIT>
__device__ __forceinline__ void scan_core(
    int grp, ushort_t (*hb)[4096],
    const float* xp, int xp_stride, int xp_col,
    float* hout, int out_col,
    const float* Wrec, const float* Wmask, const float* tau_raw,
    const float* Wf, const float* bfv, float* xf,
    unsigned int* flag)
{
    const int tid  = threadIdx.x;
    const int lane = tid & 63;
    const int wv   = tid >> 6;     // 0..3
    const int quad = lane >> 4;
    const int l15  = lane & 15;
    const int n0   = wv * 64;
    const int bg   = grp * 8;

    bf16x8 Bf[4][8];
    #pragma unroll
    for (int tc = 0; tc < 4; ++tc)
        #pragma unroll
        for (int kk = 0; kk < 8; ++kk)
            Bf[tc][kk] = load_bfrag(Wrec, Wmask,
                (size_t)(n0 + tc * 16 + l15) * H_ + kk * 32 + quad * 8);

    float inv_tau[4], h_prev[4][2];
    float xp_c[4][2], xp_n[4][2], xp_nn[4][2];
    #pragma unroll
    for (int tc = 0; tc < 4; ++tc) {
        inv_tau[tc] = 1.0f / (logf(1.0f + __expf(tau_raw[n0 + tc * 16 + l15])) + 0.1f);
        #pragma unroll
        for (int reg = 0; reg < 2; ++reg) {
            h_prev[tc][reg] = 0.0f;
            xp_c[tc][reg] = xp_n[tc][reg] = xp_nn[tc][reg] = 0.0f;
        }
    }

    int woff[4][2];
    #pragma unroll
    for (int tc = 0; tc < 4; ++tc)
        #pragma unroll
        for (int reg = 0; reg < 2; ++reg)
            woff[tc][reg] = a_off(quad * 4 + reg, n0 + tc * 16 + l15);

    #pragma unroll
    for (int tc = 0; tc < 4; ++tc)
        #pragma unroll
        for (int reg = 0; reg < 2; ++reg) {
            const int b = bg + quad * 2 + reg;
            const int c = n0 + tc * 16 + l15;
            xp_c[tc][reg] = xp[(size_t)(b * T_ + 0) * xp_stride + xp_col + c];
            xp_n[tc][reg] = xp[(size_t)(b * T_ + 1) * xp_stride + xp_col + c];
        }

    for (int i = tid; i < 4096; i += 256)
        ((unsigned int*)&hb[0][0])[i] = 0u;
    __syncthreads();

    for (int t = 0; t < T_; ++t) {
        const int rb = t & 1;

        bf16x8 Af[8];
        {
            const ushort_t* abase = &hb[rb][lane * 8];
            #pragma unroll
            for (int kk = 0; kk < 8; ++kk)
                Af[kk] = *(const bf16x8*)(abase + kk * 512);
        }

        if (t + 2 < T_) {
            #pragma unroll
            for (int tc = 0; tc < 4; ++tc)
                #pragma unroll
                for (int reg = 0; reg < 2; ++reg) {
                    const int b = bg + quad * 2 + reg;
                    xp_nn[tc][reg] = xp[(size_t)(b * T_ + t + 2) * xp_stride
                                        + xp_col + n0 + tc * 16 + l15];
                }
        }

        f32x4 acc[4] = {{0.f,0.f,0.f,0.f},{0.f,0.f,0.f,0.f},
                        {0.f,0.f,0.f,0.f},{0.f,0.f,0.f,0.f}};
        #pragma unroll
        for (int kk = 0; kk < 8; ++kk)
            #pragma unroll
            for (int tc = 0; tc < 4; ++tc)
                acc[tc] = __builtin_amdgcn_mfma_f32_16x16x32_bf16(
                    Af[kk], Bf[tc][kk], acc[tc], 0, 0, 0);

        #pragma unroll
        for (int tc = 0; tc < 4; ++tc) {
            const int c = n0 + tc * 16 + l15;
            #pragma unroll
            for (int reg = 0; reg < 2; ++reg) {
                const int b = bg + quad * 2 + reg;
                const float pre = xp_c[tc][reg] + acc[tc][reg];
                const float hn  = h_prev[tc][reg]
                                + (fast_tanh(pre) - h_prev[tc][reg]) * inv_tau[tc];
                h_prev[tc][reg] = hn;
                hb[rb ^ 1][woff[tc][reg]] = f2bf(hn);
                hout[(size_t)(b * T_ + t) * OW_ + out_col + c] = hn;
            }
        }
        #pragma unroll
        for (int tc = 0; tc < 4; ++tc)
            #pragma unroll
            for (int reg = 0; reg < 2; ++reg) {
                xp_c[tc][reg] = xp_n[tc][reg];
                xp_n[tc][reg] = xp_nn[tc][reg];
            }

        if (t + 1 < T_) LGKM_BARRIER();
    }
}

__global__ __launch_bounds__(256, 1)
void ltc_single(const float* xp, int xp_stride, int xp_col,
                float* hout, int out_col,
                const float* __restrict__ Wr, const float* __restrict__ mk,
                const float* __restrict__ tu)
{
    __shared__ __align__(16) ushort_t hb[2][4096];
    scan_core<false, false>(blockIdx.x, hb, xp, xp_stride, xp_col,
                            hout, out_col, Wr, mk, tu,
                            nullptr, nullptr, nullptr, nullptr);
}

// ---------------------------------------------------------------------------
// Proj (unchanged, passing): dst[r][dst_col+n] = bias[n] + src@Wi^T
// ---------------------------------------------------------------------------
__global__ __launch_bounds__(512, 2)
void proj_mfma(const float* __restrict__ src, int src_stride, int src_col,
               const int* __restrict__ tok,
               const float* __restrict__ Wi,
               const float* __restrict__ bias,
               float* __restrict__ dst, int dst_stride, int dst_col)
{
    const int tid  = threadIdx.x;
    const int lane = tid & 63;
    const int wv   = tid >> 6;
    const int quad = lane >> 4;
    const int l15  = lane & 15;
    const int n0   = wv * 32;

    __shared__ __align__(16) ushort_t As[32][LP];

    bf16x8 Bf[2][8];
    float  bj[2];
    #pragma unroll
    for (int tc = 0; tc < 2; ++tc) {
        const int n = n0 + tc * 16 + l15;
        bj[tc] = bias[n];
        #pragma unroll
        for (int kk = 0; kk < 8; ++kk)
            Bf[tc][kk] = load_bfrag(Wi, nullptr, (size_t)n * H_ + kk * 32 + quad * 8);
    }

    const int r0 = blockIdx.x * 32;
    {
        const int row = tid >> 4;
        const int seg = tid & 15;
        const size_t sb = (tok ? (size_t)tok[r0 + row] : (size_t)(r0 + row))
                          * src_stride + src_col + seg * 16;
        union { uint4 q[2]; ushort_t u[16]; } p;
        #pragma unroll
        for (int h = 0; h < 2; ++h) {
            float4 f0 = *(const float4*)(src + sb + h * 8);
            float4 f1 = *(const float4*)(src + sb + h * 8 + 4);
            p.u[h*8+0] = f2bf(f0.x); p.u[h*8+1] = f2bf(f0.y);
            p.u[h*8+2] = f2bf(f0.z); p.u[h*8+3] = f2bf(f0.w);
            p.u[h*8+4] = f2bf(f1.x); p.u[h*8+5] = f2bf(f1.y);
            p.u[h*8+6] = f2bf(f1.z); p.u[h*8+7] = f2bf(f1.w);
        }
        *(uint4*)&As[row][seg * 16]     = p.q[0];
        *(uint4*)&As[row][seg * 16 + 8] = p.q[1];
    }
    __syncthreads();

    #pragma unroll
    for (int rt = 0; rt < 2; ++rt) {
        bf16x8 Af[8];
        #pragma unroll
        for (int kk = 0; kk < 8; ++kk)
            Af[kk] = *(const bf16x8*)&As[rt * 16 + l15][kk * 32 + quad * 8];

        f32x4 acc[2] = {{bj[0],bj[0],bj[0],bj[0]}, {bj[1],bj[1],bj[1],bj[1]}};
        #pragma unroll
        for (int kk = 0; kk < 8; ++kk)
            #pragma unroll
            for (int tc = 0; tc < 2; ++tc)
                acc[tc] = __builtin_amdgcn_mfma_f32_16x16x32_bf16(
                    Af[kk], Bf[tc][kk], acc[tc], 0, 0, 0);

        #pragma unroll
        for (int tc = 0; tc < 2; ++tc) {
            const int c = n0 + tc * 16 + l15;
            #pragma unroll
            for (int reg = 0; reg < 4; ++reg) {
                const int r = r0 + rt * 16 + quad * 4 + reg;
                dst[(size_t)r * dst_stride + dst_col + c] = acc[tc][reg];
            }
        }
    }
}

extern "C" void kernel_launch(void* const* d_in, const int* in_sizes, int n_in,
                              void* d_out, int out_size, void* d_ws, size_t ws_size,
                              hipStream_t stream)
{
    const int*   tokens = (const int*)d_in[0];
    const float* emb    = (const float*)d_in[1];
    const float* W_in0  = (const float*)d_in[2];
    const float* W_rec0 = (const float*)d_in[3];
    const float* b0     = (const float*)d_in[4];
    const float* tau0   = (const float*)d_in[5];
    const float* mask0  = (const float*)d_in[6];
    const float* W_in1  = (const float*)d_in[7];
    const float* W_rec1 = (const float*)d_in[8];
    const float* b1     = (const float*)d_in[9];
    const float* tau1   = (const float*)d_in[10];
    const float* mask1  = (const float*)d_in[11];
    float* out = (float*)d_out;    // [8192, 512] f32
    (void)in_sizes; (void)n_in; (void)out_size;

    const size_t pk_bytes = (size_t)3 * 128 * 64 * 16;   // 384 KiB

    if (ws_size >= pk_bytes) {
        bf16x8* pk = (bf16x8*)d_ws;
        pack_frags<<<dim3(384), dim3(64), 0, stream>>>(
            W_rec0, mask0, W_in1, W_rec1, mask1, pk);
        // proj0: emb-gather GEMM -> xp0 in out cols 256..511
        proj_mfma<<<dim3(256), dim3(512), 0, stream>>>(
            emb, E_, 0, tokens, W_in0, b0, out, OW_, H_);
        ltc_merged<<<dim3(8), dim3(512), 0, stream>>>(
            out, pk, tau0, b1, tau1);
    } else {
        proj_mfma<<<dim3(256), dim3(512), 0, stream>>>(
            emb, E_, 0, tokens, W_in0, b0, out, OW_, H_);
        ltc_single<<<dim3(8), dim3(256), 0, stream>>>(
            out, OW_, H_, out, 0, W_rec0, mask0, tau0);
        proj_mfma<<<dim3(256), dim3(512), 0, stream>>>(
            out, OW_, 0, nullptr, W_in1, b1, out, OW_, H_);
        ltc_single<<<dim3(8), dim3(256), 0, stream>>>(
            out, OW_, H_, out, H_, W_rec1, mask1, tau1);
    }
}

// Round 3
// 270.789 us; speedup vs baseline: 1.8291x; 1.8291x over previous
//
#include <hip/hip_runtime.h>
#include <hip/hip_bf16.h>

#define B_ 64
#define T_ 128
#define E_ 256
#define H_ 256
#define OW_ 512   // output row width = 2*H (elements)
#define LP 264    // LDS bf16 row pitch for proj_mfma staging (elements)
#define MAGIC 0x5AD00000u

typedef unsigned short ushort_t;
typedef __attribute__((ext_vector_type(8))) short bf16x8;   // 8 bf16 = 4 VGPRs
typedef __attribute__((ext_vector_type(4))) float f32x4;    // 4 f32 acc

// Workgroup barrier WITHOUT the compiler's vmcnt(0) drain (validated r7/r8).
#define LGKM_BARRIER() asm volatile("s_waitcnt lgkmcnt(0)\n\ts_barrier" ::: "memory")

__device__ __forceinline__ ushort_t f2bf(float f) {
    unsigned int x = __float_as_uint(f);
    unsigned int r = x + 0x7FFFu + ((x >> 16) & 1u);
    return (ushort_t)(r >> 16);
}
__device__ __forceinline__ float fast_tanh(float x) {
    float e = __expf(2.0f * x);
    return 1.0f - 2.0f * __builtin_amdgcn_rcpf(e + 1.0f);
}
__device__ __forceinline__ bf16x8 load_bfrag(const float* W, const float* M,
                                             size_t base) {
    float4 a = *(const float4*)(W + base);
    float4 b = *(const float4*)(W + base + 4);
    if (M) {
        float4 ma = *(const float4*)(M + base);
        float4 mb = *(const float4*)(M + base + 4);
        a.x *= ma.x; a.y *= ma.y; a.z *= ma.z; a.w *= ma.w;
        b.x *= mb.x; b.y *= mb.y; b.z *= mb.z; b.w *= mb.w;
    }
    union { bf16x8 v; ushort_t u[8]; } r;
    r.u[0] = f2bf(a.x); r.u[1] = f2bf(a.y); r.u[2] = f2bf(a.z); r.u[3] = f2bf(a.w);
    r.u[4] = f2bf(b.x); r.u[5] = f2bf(b.y); r.u[6] = f2bf(b.z); r.u[7] = f2bf(b.w);
    return r.v;
}

// Fragment-major LDS A-layout (r9/r10-verified correct): element (r,k) at
//   off = (k>>5)*512 + ((k>>3)&3)*128 + r*8 + (k&7)
// Reader lane L reads frag kk as ds_read_b128 at element L*8 + kk*512
// (= A-row l15, k = kk*32 + quad*8 + j): exact MFMA A-frag, linear in lane
// -> conflict-free reads. Pad-row lanes ((l15&2)!=0; their C rows are
// discarded) read a broadcast address instead -> ~half LDS read volume.
__device__ __forceinline__ int a_off(int r, int k) {
    return ((k >> 5) << 9) + (((k >> 3) & 3) << 7) + (r << 3) + (k & 7);
}

// ---------------------------------------------------------------------------
// scan_core<FUSE,WAIT> (r11): r8 structure (8 waves x TC=2, 512 thr,
// producer/consumer over 16 WGs) + frag-major A-tiles + broadcast-pad reads.
// KEY FIX vs r8: callers use __launch_bounds__(512,1) -> 256-VGPR budget so
// the FUSE producer holds BOTH weight matrices (Bf+Bf2 = 128 VGPRs) resident
// (r8's 128-cap forced silent per-step weight reloads from L2, ~2000 cy/step
// of single-CU memory-port traffic - the dominant producer cost).
// Batch row i at A-slot (i>>1)*4+(i&1); C rows quad*4+reg (reg<2) ->
// lane(quad,l15) owns batches {quad*2,quad*2+1} x cols {wv*32+tc*16+l15}.
// FUSE: also computes xp1(t-1) = h0(t-1) @ Wf^T + bf with the same A-frags,
//   agent-scope stores, publishes 8-row chunks via vmcnt-draining
//   __syncthreads + release flag.  WAIT: spins (acquire, poison-tolerant
//   window) for each 8-row xp chunk.  Neither: standalone fallback.
// ---------------------------------------------------------------------------
template<bool FUSE, bool WAIT>
__device__ __forceinline__ void scan_core(
    int grp, ushort_t (*hb)[4096],
    const float* xp, int xp_stride, int xp_col,
    float* hout, int out_col,
    const float* Wrec, const float* Wmask, const float* tau_raw,
    const float* Wf, const float* bfv, float* xf,
    unsigned int* flag)
{
    const int tid  = threadIdx.x;
    const int lane = tid & 63;
    const int wv   = tid >> 6;     // 0..7
    const int quad = lane >> 4;
    const int l15  = lane & 15;
    const int n0   = wv * 32;
    const int bg   = grp * 8;

    bf16x8 Bf[2][8];
    #pragma unroll
    for (int tc = 0; tc < 2; ++tc)
        #pragma unroll
        for (int kk = 0; kk < 8; ++kk)
            Bf[tc][kk] = load_bfrag(Wrec, Wmask,
                (size_t)(n0 + tc * 16 + l15) * H_ + kk * 32 + quad * 8);

    bf16x8 Bf2[2][8];
    float  b2[2] = {0.f, 0.f};
    if (FUSE) {
        #pragma unroll
        for (int tc = 0; tc < 2; ++tc) {
            b2[tc] = bfv[n0 + tc * 16 + l15];
            #pragma unroll
            for (int kk = 0; kk < 8; ++kk)
                Bf2[tc][kk] = load_bfrag(Wf, nullptr,
                    (size_t)(n0 + tc * 16 + l15) * H_ + kk * 32 + quad * 8);
        }
    }

    float inv_tau[2], h_prev[2][2];
    float xp_c[2][2], xp_n[2][2], xp_nn[2][2];
    #pragma unroll
    for (int tc = 0; tc < 2; ++tc) {
        inv_tau[tc] = 1.0f / (logf(1.0f + __expf(tau_raw[n0 + tc * 16 + l15])) + 0.1f);
        #pragma unroll
        for (int reg = 0; reg < 2; ++reg) {
            h_prev[tc][reg] = 0.0f;
            xp_c[tc][reg] = xp_n[tc][reg] = xp_nn[tc][reg] = 0.0f;
        }
    }

    // frag-major write offsets; broadcast A-read base for pad-row lanes
    int woff[2][2];
    #pragma unroll
    for (int tc = 0; tc < 2; ++tc)
        #pragma unroll
        for (int reg = 0; reg < 2; ++reg)
            woff[tc][reg] = a_off(quad * 4 + reg, n0 + tc * 16 + l15);
    const int ab = ((l15 & 2) == 0) ? (lane * 8) : 0;

    if (!WAIT) {   // prologue loads for t=0,1 (WAIT loads at chunk tops)
        #pragma unroll
        for (int tc = 0; tc < 2; ++tc)
            #pragma unroll
            for (int reg = 0; reg < 2; ++reg) {
                const int b = bg + quad * 2 + reg;
                const int c = n0 + tc * 16 + l15;
                xp_c[tc][reg] = xp[(size_t)(b * T_ + 0) * xp_stride + xp_col + c];
                xp_n[tc][reg] = xp[(size_t)(b * T_ + 1) * xp_stride + xp_col + c];
            }
    }

    for (int i = tid; i < 4096; i += 512)
        ((unsigned int*)&hb[0][0])[i] = 0u;   // zero both buffers (16 KB)
    __syncthreads();

    const int tmax = FUSE ? T_ : (T_ - 1);
    for (int t = 0; t <= tmax; ++t) {
        const int rb = t & 1;

        if (WAIT && t < T_ && (t & 7) == 0) {
            if (tid == 0) {
                const unsigned need = (unsigned)(t >> 3) + 1u;
                for (;;) {
                    unsigned d = __hip_atomic_load(flag, __ATOMIC_ACQUIRE,
                                                   __HIP_MEMORY_SCOPE_AGENT) - MAGIC;
                    if (d >= need && d <= 16u) break;
                    __builtin_amdgcn_s_sleep(2);
                }
            }
            __syncthreads();
            #pragma unroll
            for (int tc = 0; tc < 2; ++tc)
                #pragma unroll
                for (int reg = 0; reg < 2; ++reg) {
                    const int b = bg + quad * 2 + reg;
                    xp_c[tc][reg] = xp[(size_t)(b * T_ + t) * xp_stride + xp_col
                                       + n0 + tc * 16 + l15];
                }
        }

        // A fragments (h(t-1)); shared by recurrence and fused projection.
        // Linear ds_read_b128; pad lanes broadcast -> conflict-free, 1/2 volume.
        bf16x8 Af[8];
        {
            const ushort_t* a0 = &hb[rb][0];
            #pragma unroll
            for (int kk = 0; kk < 8; ++kk)
                Af[kk] = *(const bf16x8*)(a0 + ab + kk * 512);
        }

        if (t < T_) {
            // prefetch
            if (WAIT) {
                if ((t & 7) != 7 && t + 1 < T_) {
                    #pragma unroll
                    for (int tc = 0; tc < 2; ++tc)
                        #pragma unroll
                        for (int reg = 0; reg < 2; ++reg) {
                            const int b = bg + quad * 2 + reg;
                            xp_n[tc][reg] = xp[(size_t)(b * T_ + t + 1) * xp_stride
                                               + xp_col + n0 + tc * 16 + l15];
                        }
                }
            } else if (t + 2 < T_) {
                #pragma unroll
                for (int tc = 0; tc < 2; ++tc)
                    #pragma unroll
                    for (int reg = 0; reg < 2; ++reg) {
                        const int b = bg + quad * 2 + reg;
                        xp_nn[tc][reg] = xp[(size_t)(b * T_ + t + 2) * xp_stride
                                            + xp_col + n0 + tc * 16 + l15];
                    }
            }

            f32x4 acc[2] = {{0.f,0.f,0.f,0.f},{0.f,0.f,0.f,0.f}};
            #pragma unroll
            for (int kk = 0; kk < 8; ++kk)
                #pragma unroll
                for (int tc = 0; tc < 2; ++tc)
                    acc[tc] = __builtin_amdgcn_mfma_f32_16x16x32_bf16(
                        Af[kk], Bf[tc][kk], acc[tc], 0, 0, 0);

            #pragma unroll
            for (int tc = 0; tc < 2; ++tc) {
                const int c = n0 + tc * 16 + l15;
                #pragma unroll
                for (int reg = 0; reg < 2; ++reg) {
                    const int b = bg + quad * 2 + reg;
                    const float pre = xp_c[tc][reg] + acc[tc][reg];
                    const float hn  = h_prev[tc][reg]
                                    + (fast_tanh(pre) - h_prev[tc][reg]) * inv_tau[tc];
                    h_prev[tc][reg] = hn;
                    hb[rb ^ 1][woff[tc][reg]] = f2bf(hn);
                    hout[(size_t)(b * T_ + t) * OW_ + out_col + c] = hn;
                }
            }
            if (WAIT) {
                if ((t & 7) != 7) {
                    #pragma unroll
                    for (int tc = 0; tc < 2; ++tc)
                        #pragma unroll
                        for (int reg = 0; reg < 2; ++reg)
                            xp_c[tc][reg] = xp_n[tc][reg];
                }
            } else {
                #pragma unroll
                for (int tc = 0; tc < 2; ++tc)
                    #pragma unroll
                    for (int reg = 0; reg < 2; ++reg) {
                        xp_c[tc][reg] = xp_n[tc][reg];
                        xp_n[tc][reg] = xp_nn[tc][reg];
                    }
            }
        }

        if (FUSE && t > 0) {
            f32x4 acc2[2];
            #pragma unroll
            for (int tc = 0; tc < 2; ++tc)
                acc2[tc] = (f32x4){b2[tc], b2[tc], b2[tc], b2[tc]};
            #pragma unroll
            for (int kk = 0; kk < 8; ++kk)
                #pragma unroll
                for (int tc = 0; tc < 2; ++tc)
                    acc2[tc] = __builtin_amdgcn_mfma_f32_16x16x32_bf16(
                        Af[kk], Bf2[tc][kk], acc2[tc], 0, 0, 0);
            #pragma unroll
            for (int tc = 0; tc < 2; ++tc) {
                const int c = n0 + tc * 16 + l15;
                #pragma unroll
                for (int reg = 0; reg < 2; ++reg) {
                    const int b = bg + quad * 2 + reg;
                    // agent-scope store: cross-XCD visible once retired
                    __hip_atomic_store(&xf[(size_t)(b * T_ + t - 1) * H_ + c],
                                       acc2[tc][reg],
                                       __ATOMIC_RELAXED, __HIP_MEMORY_SCOPE_AGENT);
                }
            }
        }

        if (FUSE && t > 0 && (t & 7) == 0) {
            __syncthreads();   // drains vmcnt -> all xf stores of rows < t retired
            if (tid == 0)
                __hip_atomic_store(flag, MAGIC + (unsigned)(t >> 3),
                                   __ATOMIC_RELEASE, __HIP_MEMORY_SCOPE_AGENT);
        } else if (t < tmax) {
            LGKM_BARRIER();
        }
    }
}

// Single dispatch: WGs 0..7 = level-0 producers (scan0 + fused xp1),
// WGs 8..15 = level-1 consumers (scan1), pipelined 8 steps behind.
// launch_bounds(512,1): 256-VGPR budget (grid 16 on 256 CUs -> 1 blk/CU free)
__global__ __launch_bounds__(512, 1)
void ltc_dual(float* out,
              const float* __restrict__ Wr0, const float* __restrict__ m0,
              const float* __restrict__ t0,
              const float* __restrict__ Wi1, const float* __restrict__ b1v,
              const float* __restrict__ Wr1, const float* __restrict__ m1,
              const float* __restrict__ t1,
              float* xf, unsigned int* flags)
{
    __shared__ __align__(16) ushort_t hb[2][4096];
    if (blockIdx.x < 8)
        scan_core<true, false>(blockIdx.x, hb,
                               out, OW_, H_,     // xp0 in out cols 256..511
                               out, 0,           // h0 -> cols 0..255
                               Wr0, m0, t0, Wi1, b1v, xf, flags + blockIdx.x);
    else
        scan_core<false, true>(blockIdx.x - 8, hb,
                               xf, H_, 0,        // xp1 from workspace
                               out, H_,          // h1 -> cols 256..511
                               Wr1, m1, t1, nullptr, nullptr, nullptr,
                               flags + blockIdx.x - 8);
}

// Fallback standalone scan (no workspace): alias-safe path (reads row t+2
// before writing row t; same-thread program order).
__global__ __launch_bounds__(512, 1)
void ltc_single(const float* xp, int xp_stride, int xp_col,
                float* hout, int out_col,
                const float* __restrict__ Wr, const float* __restrict__ mk,
                const float* __restrict__ tu)
{
    __shared__ __align__(16) ushort_t hb[2][4096];
    scan_core<false, false>(blockIdx.x, hb, xp, xp_stride, xp_col,
                            hout, out_col, Wr, mk, tu,
                            nullptr, nullptr, nullptr, nullptr);
}

// ---------------------------------------------------------------------------
// Proj (unchanged, passing): dst[r][dst_col+n] = bias[n] + src@Wi^T
// ---------------------------------------------------------------------------
__global__ __launch_bounds__(512, 2)
void proj_mfma(const float* __restrict__ src, int src_stride, int src_col,
               const int* __restrict__ tok,
               const float* __restrict__ Wi,
               const float* __restrict__ bias,
               float* __restrict__ dst, int dst_stride, int dst_col)
{
    const int tid  = threadIdx.x;
    const int lane = tid & 63;
    const int wv   = tid >> 6;
    const int quad = lane >> 4;
    const int l15  = lane & 15;
    const int n0   = wv * 32;

    __shared__ __align__(16) ushort_t As[32][LP];

    bf16x8 Bf[2][8];
    float  bj[2];
    #pragma unroll
    for (int tc = 0; tc < 2; ++tc) {
        const int n = n0 + tc * 16 + l15;
        bj[tc] = bias[n];
        #pragma unroll
        for (int kk = 0; kk < 8; ++kk)
            Bf[tc][kk] = load_bfrag(Wi, nullptr, (size_t)n * H_ + kk * 32 + quad * 8);
    }

    const int r0 = blockIdx.x * 32;
    {
        const int row = tid >> 4;
        const int seg = tid & 15;
        const size_t sb = (tok ? (size_t)tok[r0 + row] : (size_t)(r0 + row))
                          * src_stride + src_col + seg * 16;
        union { uint4 q[2]; ushort_t u[16]; } p;
        #pragma unroll
        for (int h = 0; h < 2; ++h) {
            float4 f0 = *(const float4*)(src + sb + h * 8);
            float4 f1 = *(const float4*)(src + sb + h * 8 + 4);
            p.u[h*8+0] = f2bf(f0.x); p.u[h*8+1] = f2bf(f0.y);
            p.u[h*8+2] = f2bf(f0.z); p.u[h*8+3] = f2bf(f0.w);
            p.u[h*8+4] = f2bf(f1.x); p.u[h*8+5] = f2bf(f1.y);
            p.u[h*8+6] = f2bf(f1.z); p.u[h*8+7] = f2bf(f1.w);
        }
        *(uint4*)&As[row][seg * 16]     = p.q[0];
        *(uint4*)&As[row][seg * 16 + 8] = p.q[1];
    }
    __syncthreads();

    #pragma unroll
    for (int rt = 0; rt < 2; ++rt) {
        bf16x8 Af[8];
        #pragma unroll
        for (int kk = 0; kk < 8; ++kk)
            Af[kk] = *(const bf16x8*)&As[rt * 16 + l15][kk * 32 + quad * 8];

        f32x4 acc[2] = {{bj[0],bj[0],bj[0],bj[0]}, {bj[1],bj[1],bj[1],bj[1]}};
        #pragma unroll
        for (int kk = 0; kk < 8; ++kk)
            #pragma unroll
            for (int tc = 0; tc < 2; ++tc)
                acc[tc] = __builtin_amdgcn_mfma_f32_16x16x32_bf16(
                    Af[kk], Bf[tc][kk], acc[tc], 0, 0, 0);

        #pragma unroll
        for (int tc = 0; tc < 2; ++tc) {
            const int c = n0 + tc * 16 + l15;
            #pragma unroll
            for (int reg = 0; reg < 4; ++reg) {
                const int r = r0 + rt * 16 + quad * 4 + reg;
                dst[(size_t)r * dst_stride + dst_col + c] = acc[tc][reg];
            }
        }
    }
}

extern "C" void kernel_launch(void* const* d_in, const int* in_sizes, int n_in,
                              void* d_out, int out_size, void* d_ws, size_t ws_size,
                              hipStream_t stream)
{
    const int*   tokens = (const int*)d_in[0];
    const float* emb    = (const float*)d_in[1];
    const float* W_in0  = (const float*)d_in[2];
    const float* W_rec0 = (const float*)d_in[3];
    const float* b0     = (const float*)d_in[4];
    const float* tau0   = (const float*)d_in[5];
    const float* mask0  = (const float*)d_in[6];
    const float* W_in1  = (const float*)d_in[7];
    const float* W_rec1 = (const float*)d_in[8];
    const float* b1     = (const float*)d_in[9];
    const float* tau1   = (const float*)d_in[10];
    const float* mask1  = (const float*)d_in[11];
    float* out = (float*)d_out;    // [8192, 512] f32
    (void)in_sizes; (void)n_in; (void)out_size;

    const size_t xf_elems = (size_t)B_ * T_ * H_;
    const bool pipelined = ws_size >= xf_elems * sizeof(float) + 64;

    // proj0: emb-gather GEMM -> xp0 in out cols 256..511
    proj_mfma<<<dim3(256), dim3(512), 0, stream>>>(
        emb, E_, 0, tokens, W_in0, b0, out, OW_, H_);

    if (pipelined) {
        float* xf = (float*)d_ws;
        unsigned int* flags = (unsigned int*)((float*)d_ws + xf_elems);
        // flags arrive poisoned (0xAA..) each launch; consumers' window check
        // treats poison as not-ready; producers overwrite with MAGIC+c.
        ltc_dual<<<dim3(16), dim3(512), 0, stream>>>(
            out, W_rec0, mask0, tau0, W_in1, b1, W_rec1, mask1, tau1, xf, flags);
    } else {
        ltc_single<<<dim3(8), dim3(512), 0, stream>>>(
            out, OW_, H_, out, 0, W_rec0, mask0, tau0);
        proj_mfma<<<dim3(256), dim3(512), 0, stream>>>(
            out, OW_, 0, nullptr, W_in1, b1, out, OW_, H_);
        ltc_single<<<dim3(8), dim3(512), 0, stream>>>(
            out, OW_, H_, out, H_, W_rec1, mask1, tau1);
    }
}

// Round 4
// 260.851 us; speedup vs baseline: 1.8987x; 1.0381x over previous
//
#include <hip/hip_runtime.h>
#include <hip/hip_bf16.h>

#define B_ 64
#define T_ 128
#define E_ 256
#define H_ 256
#define OW_ 512   // output row width = 2*H (elements)
#define LP 264    // LDS bf16 row pitch for proj_mfma staging (elements)
#define MAGIC 0x5AD00000u

typedef unsigned short ushort_t;
typedef __attribute__((ext_vector_type(8))) short bf16x8;   // 8 bf16 = 4 VGPRs
typedef __attribute__((ext_vector_type(4))) float f32x4;    // 4 f32 acc

// Workgroup barrier WITHOUT the compiler's vmcnt(0) drain (validated r7/r8).
#define LGKM_BARRIER() asm volatile("s_waitcnt lgkmcnt(0)\n\ts_barrier" ::: "memory")

// Force a fragment to be loop-carried (resident in VGPRs): empty asm with
// read-write register constraint. Prevents LLVM from sinking the weight
// loads (+bf16 converts) into the scan loop and re-executing them per step.
#define PIN_FRAG(x) asm volatile("" : "+v"(x))

__device__ __forceinline__ ushort_t f2bf(float f) {
    unsigned int x = __float_as_uint(f);
    unsigned int r = x + 0x7FFFu + ((x >> 16) & 1u);
    return (ushort_t)(r >> 16);
}
__device__ __forceinline__ float fast_tanh(float x) {
    float e = __expf(2.0f * x);
    return 1.0f - 2.0f * __builtin_amdgcn_rcpf(e + 1.0f);
}
__device__ __forceinline__ bf16x8 load_bfrag(const float* W, const float* M,
                                             size_t base) {
    float4 a = *(const float4*)(W + base);
    float4 b = *(const float4*)(W + base + 4);
    if (M) {
        float4 ma = *(const float4*)(M + base);
        float4 mb = *(const float4*)(M + base + 4);
        a.x *= ma.x; a.y *= ma.y; a.z *= ma.z; a.w *= ma.w;
        b.x *= mb.x; b.y *= mb.y; b.z *= mb.z; b.w *= mb.w;
    }
    union { bf16x8 v; ushort_t u[8]; } r;
    r.u[0] = f2bf(a.x); r.u[1] = f2bf(a.y); r.u[2] = f2bf(a.z); r.u[3] = f2bf(a.w);
    r.u[4] = f2bf(b.x); r.u[5] = f2bf(b.y); r.u[6] = f2bf(b.z); r.u[7] = f2bf(b.w);
    return r.v;
}

// Fragment-major LDS A-layout (r9-verified): element (r,k) at
//   off = (k>>5)*512 + ((k>>3)&3)*128 + r*8 + (k&7)
// Reader lane L reads frag kk as ds_read_b128 at element L*8 + kk*512
// (= A-row l15, k = kk*32 + quad*8 + j): exact MFMA A-frag, linear in lane
// -> conflict-free reads. Pad-row lanes ((l15&2)!=0; their C rows are
// discarded) read a broadcast address instead -> ~half LDS read volume.
__device__ __forceinline__ int a_off(int r, int k) {
    return ((k >> 5) << 9) + (((k >> 3) & 3) << 7) + (r << 3) + (k & 7);
}

// ---------------------------------------------------------------------------
// scan_core<FUSE,WAIT> (r12): r11 structure (8 waves x TC=2, 512 thr,
// producer/consumer over 16 WGs, frag-major A-tiles, broadcast-pad reads)
// + PIN_FRAG on the weight fragments inside the scan loop.
// r11 showed VGPR_Count=128 despite launch_bounds(512,1): the allocator was
// still re-loading + re-converting the weight matrices from L2 every step
// (launch bounds permit 256 VGPRs but don't force residency). The pins make
// the fragments loop-carried -> must stay in registers.
// Batch row i at A-slot (i>>1)*4+(i&1); C rows quad*4+reg (reg<2) ->
// lane(quad,l15) owns batches {quad*2,quad*2+1} x cols {wv*32+tc*16+l15}.
// FUSE: also computes xp1(t-1) = h0(t-1) @ Wf^T + bf with the same A-frags,
//   agent-scope stores, publishes 8-row chunks via vmcnt-draining
//   __syncthreads + release flag.  WAIT: spins (acquire, poison-tolerant
//   window) for each 8-row xp chunk.  Neither: standalone fallback.
// ---------------------------------------------------------------------------
template<bool FUSE, bool WAIT>
__device__ __forceinline__ void scan_core(
    int grp, ushort_t (*hb)[4096],
    const float* xp, int xp_stride, int xp_col,
    float* hout, int out_col,
    const float* Wrec, const float* Wmask, const float* tau_raw,
    const float* Wf, const float* bfv, float* xf,
    unsigned int* flag)
{
    const int tid  = threadIdx.x;
    const int lane = tid & 63;
    const int wv   = tid >> 6;     // 0..7
    const int quad = lane >> 4;
    const int l15  = lane & 15;
    const int n0   = wv * 32;
    const int bg   = grp * 8;

    bf16x8 Bf[2][8];
    #pragma unroll
    for (int tc = 0; tc < 2; ++tc)
        #pragma unroll
        for (int kk = 0; kk < 8; ++kk)
            Bf[tc][kk] = load_bfrag(Wrec, Wmask,
                (size_t)(n0 + tc * 16 + l15) * H_ + kk * 32 + quad * 8);

    bf16x8 Bf2[2][8];
    float  b2[2] = {0.f, 0.f};
    if (FUSE) {
        #pragma unroll
        for (int tc = 0; tc < 2; ++tc) {
            b2[tc] = bfv[n0 + tc * 16 + l15];
            #pragma unroll
            for (int kk = 0; kk < 8; ++kk)
                Bf2[tc][kk] = load_bfrag(Wf, nullptr,
                    (size_t)(n0 + tc * 16 + l15) * H_ + kk * 32 + quad * 8);
        }
    }

    float inv_tau[2], h_prev[2][2];
    float xp_c[2][2], xp_n[2][2], xp_nn[2][2];
    #pragma unroll
    for (int tc = 0; tc < 2; ++tc) {
        inv_tau[tc] = 1.0f / (logf(1.0f + __expf(tau_raw[n0 + tc * 16 + l15])) + 0.1f);
        #pragma unroll
        for (int reg = 0; reg < 2; ++reg) {
            h_prev[tc][reg] = 0.0f;
            xp_c[tc][reg] = xp_n[tc][reg] = xp_nn[tc][reg] = 0.0f;
        }
    }

    // frag-major write offsets; broadcast A-read base for pad-row lanes
    int woff[2][2];
    #pragma unroll
    for (int tc = 0; tc < 2; ++tc)
        #pragma unroll
        for (int reg = 0; reg < 2; ++reg)
            woff[tc][reg] = a_off(quad * 4 + reg, n0 + tc * 16 + l15);
    const int ab = ((l15 & 2) == 0) ? (lane * 8) : 0;

    if (!WAIT) {   // prologue loads for t=0,1 (WAIT loads at chunk tops)
        #pragma unroll
        for (int tc = 0; tc < 2; ++tc)
            #pragma unroll
            for (int reg = 0; reg < 2; ++reg) {
                const int b = bg + quad * 2 + reg;
                const int c = n0 + tc * 16 + l15;
                xp_c[tc][reg] = xp[(size_t)(b * T_ + 0) * xp_stride + xp_col + c];
                xp_n[tc][reg] = xp[(size_t)(b * T_ + 1) * xp_stride + xp_col + c];
            }
    }

    for (int i = tid; i < 4096; i += 512)
        ((unsigned int*)&hb[0][0])[i] = 0u;   // zero both buffers (16 KB)
    __syncthreads();

    const int tmax = FUSE ? T_ : (T_ - 1);
    for (int t = 0; t <= tmax; ++t) {
        const int rb = t & 1;

        // Keep weight fragments loop-carried (see header comment).
        #pragma unroll
        for (int tc = 0; tc < 2; ++tc)
            #pragma unroll
            for (int kk = 0; kk < 8; ++kk) {
                PIN_FRAG(Bf[tc][kk]);
                if (FUSE) PIN_FRAG(Bf2[tc][kk]);
            }

        if (WAIT && t < T_ && (t & 7) == 0) {
            if (tid == 0) {
                const unsigned need = (unsigned)(t >> 3) + 1u;
                for (;;) {
                    unsigned d = __hip_atomic_load(flag, __ATOMIC_ACQUIRE,
                                                   __HIP_MEMORY_SCOPE_AGENT) - MAGIC;
                    if (d >= need && d <= 16u) break;
                    __builtin_amdgcn_s_sleep(2);
                }
            }
            __syncthreads();
            #pragma unroll
            for (int tc = 0; tc < 2; ++tc)
                #pragma unroll
                for (int reg = 0; reg < 2; ++reg) {
                    const int b = bg + quad * 2 + reg;
                    xp_c[tc][reg] = xp[(size_t)(b * T_ + t) * xp_stride + xp_col
                                       + n0 + tc * 16 + l15];
                }
        }

        // A fragments (h(t-1)); shared by recurrence and fused projection.
        // Linear ds_read_b128; pad lanes broadcast -> conflict-free, 1/2 volume.
        bf16x8 Af[8];
        {
            const ushort_t* a0 = &hb[rb][0];
            #pragma unroll
            for (int kk = 0; kk < 8; ++kk)
                Af[kk] = *(const bf16x8*)(a0 + ab + kk * 512);
        }

        if (t < T_) {
            // prefetch
            if (WAIT) {
                if ((t & 7) != 7 && t + 1 < T_) {
                    #pragma unroll
                    for (int tc = 0; tc < 2; ++tc)
                        #pragma unroll
                        for (int reg = 0; reg < 2; ++reg) {
                            const int b = bg + quad * 2 + reg;
                            xp_n[tc][reg] = xp[(size_t)(b * T_ + t + 1) * xp_stride
                                               + xp_col + n0 + tc * 16 + l15];
                        }
                }
            } else if (t + 2 < T_) {
                #pragma unroll
                for (int tc = 0; tc < 2; ++tc)
                    #pragma unroll
                    for (int reg = 0; reg < 2; ++reg) {
                        const int b = bg + quad * 2 + reg;
                        xp_nn[tc][reg] = xp[(size_t)(b * T_ + t + 2) * xp_stride
                                            + xp_col + n0 + tc * 16 + l15];
                    }
            }

            f32x4 acc[2] = {{0.f,0.f,0.f,0.f},{0.f,0.f,0.f,0.f}};
            #pragma unroll
            for (int kk = 0; kk < 8; ++kk)
                #pragma unroll
                for (int tc = 0; tc < 2; ++tc)
                    acc[tc] = __builtin_amdgcn_mfma_f32_16x16x32_bf16(
                        Af[kk], Bf[tc][kk], acc[tc], 0, 0, 0);

            #pragma unroll
            for (int tc = 0; tc < 2; ++tc) {
                const int c = n0 + tc * 16 + l15;
                #pragma unroll
                for (int reg = 0; reg < 2; ++reg) {
                    const int b = bg + quad * 2 + reg;
                    const float pre = xp_c[tc][reg] + acc[tc][reg];
                    const float hn  = h_prev[tc][reg]
                                    + (fast_tanh(pre) - h_prev[tc][reg]) * inv_tau[tc];
                    h_prev[tc][reg] = hn;
                    hb[rb ^ 1][woff[tc][reg]] = f2bf(hn);
                    hout[(size_t)(b * T_ + t) * OW_ + out_col + c] = hn;
                }
            }
            if (WAIT) {
                if ((t & 7) != 7) {
                    #pragma unroll
                    for (int tc = 0; tc < 2; ++tc)
                        #pragma unroll
                        for (int reg = 0; reg < 2; ++reg)
                            xp_c[tc][reg] = xp_n[tc][reg];
                }
            } else {
                #pragma unroll
                for (int tc = 0; tc < 2; ++tc)
                    #pragma unroll
                    for (int reg = 0; reg < 2; ++reg) {
                        xp_c[tc][reg] = xp_n[tc][reg];
                        xp_n[tc][reg] = xp_nn[tc][reg];
                    }
            }
        }

        if (FUSE && t > 0) {
            f32x4 acc2[2];
            #pragma unroll
            for (int tc = 0; tc < 2; ++tc)
                acc2[tc] = (f32x4){b2[tc], b2[tc], b2[tc], b2[tc]};
            #pragma unroll
            for (int kk = 0; kk < 8; ++kk)
                #pragma unroll
                for (int tc = 0; tc < 2; ++tc)
                    acc2[tc] = __builtin_amdgcn_mfma_f32_16x16x32_bf16(
                        Af[kk], Bf2[tc][kk], acc2[tc], 0, 0, 0);
            #pragma unroll
            for (int tc = 0; tc < 2; ++tc) {
                const int c = n0 + tc * 16 + l15;
                #pragma unroll
                for (int reg = 0; reg < 2; ++reg) {
                    const int b = bg + quad * 2 + reg;
                    // agent-scope store: cross-XCD visible once retired
                    __hip_atomic_store(&xf[(size_t)(b * T_ + t - 1) * H_ + c],
                                       acc2[tc][reg],
                                       __ATOMIC_RELAXED, __HIP_MEMORY_SCOPE_AGENT);
                }
            }
        }

        if (FUSE && t > 0 && (t & 7) == 0) {
            __syncthreads();   // drains vmcnt -> all xf stores of rows < t retired
            if (tid == 0)
                __hip_atomic_store(flag, MAGIC + (unsigned)(t >> 3),
                                   __ATOMIC_RELEASE, __HIP_MEMORY_SCOPE_AGENT);
        } else if (t < tmax) {
            LGKM_BARRIER();
        }
    }
}

// Single dispatch: WGs 0..7 = level-0 producers (scan0 + fused xp1),
// WGs 8..15 = level-1 consumers (scan1), pipelined 8 steps behind.
// launch_bounds(512,1): 256-VGPR budget (grid 16 on 256 CUs -> 1 blk/CU free)
__global__ __launch_bounds__(512, 1)
void ltc_dual(float* out,
              const float* __restrict__ Wr0, const float* __restrict__ m0,
              const float* __restrict__ t0,
              const float* __restrict__ Wi1, const float* __restrict__ b1v,
              const float* __restrict__ Wr1, const float* __restrict__ m1,
              const float* __restrict__ t1,
              float* xf, unsigned int* flags)
{
    __shared__ __align__(16) ushort_t hb[2][4096];
    if (blockIdx.x < 8)
        scan_core<true, false>(blockIdx.x, hb,
                               out, OW_, H_,     // xp0 in out cols 256..511
                               out, 0,           // h0 -> cols 0..255
                               Wr0, m0, t0, Wi1, b1v, xf, flags + blockIdx.x);
    else
        scan_core<false, true>(blockIdx.x - 8, hb,
                               xf, H_, 0,        // xp1 from workspace
                               out, H_,          // h1 -> cols 256..511
                               Wr1, m1, t1, nullptr, nullptr, nullptr,
                               flags + blockIdx.x - 8);
}

// Fallback standalone scan (no workspace): alias-safe path (reads row t+2
// before writing row t; same-thread program order).
__global__ __launch_bounds__(512, 1)
void ltc_single(const float* xp, int xp_stride, int xp_col,
                float* hout, int out_col,
                const float* __restrict__ Wr, const float* __restrict__ mk,
                const float* __restrict__ tu)
{
    __shared__ __align__(16) ushort_t hb[2][4096];
    scan_core<false, false>(blockIdx.x, hb, xp, xp_stride, xp_col,
                            hout, out_col, Wr, mk, tu,
                            nullptr, nullptr, nullptr, nullptr);
}

// ---------------------------------------------------------------------------
// Proj (unchanged, passing): dst[r][dst_col+n] = bias[n] + src@Wi^T
// ---------------------------------------------------------------------------
__global__ __launch_bounds__(512, 2)
void proj_mfma(const float* __restrict__ src, int src_stride, int src_col,
               const int* __restrict__ tok,
               const float* __restrict__ Wi,
               const float* __restrict__ bias,
               float* __restrict__ dst, int dst_stride, int dst_col)
{
    const int tid  = threadIdx.x;
    const int lane = tid & 63;
    const int wv   = tid >> 6;
    const int quad = lane >> 4;
    const int l15  = lane & 15;
    const int n0   = wv * 32;

    __shared__ __align__(16) ushort_t As[32][LP];

    bf16x8 Bf[2][8];
    float  bj[2];
    #pragma unroll
    for (int tc = 0; tc < 2; ++tc) {
        const int n = n0 + tc * 16 + l15;
        bj[tc] = bias[n];
        #pragma unroll
        for (int kk = 0; kk < 8; ++kk)
            Bf[tc][kk] = load_bfrag(Wi, nullptr, (size_t)n * H_ + kk * 32 + quad * 8);
    }

    const int r0 = blockIdx.x * 32;
    {
        const int row = tid >> 4;
        const int seg = tid & 15;
        const size_t sb = (tok ? (size_t)tok[r0 + row] : (size_t)(r0 + row))
                          * src_stride + src_col + seg * 16;
        union { uint4 q[2]; ushort_t u[16]; } p;
        #pragma unroll
        for (int h = 0; h < 2; ++h) {
            float4 f0 = *(const float4*)(src + sb + h * 8);
            float4 f1 = *(const float4*)(src + sb + h * 8 + 4);
            p.u[h*8+0] = f2bf(f0.x); p.u[h*8+1] = f2bf(f0.y);
            p.u[h*8+2] = f2bf(f0.z); p.u[h*8+3] = f2bf(f0.w);
            p.u[h*8+4] = f2bf(f1.x); p.u[h*8+5] = f2bf(f1.y);
            p.u[h*8+6] = f2bf(f1.z); p.u[h*8+7] = f2bf(f1.w);
        }
        *(uint4*)&As[row][seg * 16]     = p.q[0];
        *(uint4*)&As[row][seg * 16 + 8] = p.q[1];
    }
    __syncthreads();

    #pragma unroll
    for (int rt = 0; rt < 2; ++rt) {
        bf16x8 Af[8];
        #pragma unroll
        for (int kk = 0; kk < 8; ++kk)
            Af[kk] = *(const bf16x8*)&As[rt * 16 + l15][kk * 32 + quad * 8];

        f32x4 acc[2] = {{bj[0],bj[0],bj[0],bj[0]}, {bj[1],bj[1],bj[1],bj[1]}};
        #pragma unroll
        for (int kk = 0; kk < 8; ++kk)
            #pragma unroll
            for (int tc = 0; tc < 2; ++tc)
                acc[tc] = __builtin_amdgcn_mfma_f32_16x16x32_bf16(
                    Af[kk], Bf[tc][kk], acc[tc], 0, 0, 0);

        #pragma unroll
        for (int tc = 0; tc < 2; ++tc) {
            const int c = n0 + tc * 16 + l15;
            #pragma unroll
            for (int reg = 0; reg < 4; ++reg) {
                const int r = r0 + rt * 16 + quad * 4 + reg;
                dst[(size_t)r * dst_stride + dst_col + c] = acc[tc][reg];
            }
        }
    }
}

extern "C" void kernel_launch(void* const* d_in, const int* in_sizes, int n_in,
                              void* d_out, int out_size, void* d_ws, size_t ws_size,
                              hipStream_t stream)
{
    const int*   tokens = (const int*)d_in[0];
    const float* emb    = (const float*)d_in[1];
    const float* W_in0  = (const float*)d_in[2];
    const float* W_rec0 = (const float*)d_in[3];
    const float* b0     = (const float*)d_in[4];
    const float* tau0   = (const float*)d_in[5];
    const float* mask0  = (const float*)d_in[6];
    const float* W_in1  = (const float*)d_in[7];
    const float* W_rec1 = (const float*)d_in[8];
    const float* b1     = (const float*)d_in[9];
    const float* tau1   = (const float*)d_in[10];
    const float* mask1  = (const float*)d_in[11];
    float* out = (float*)d_out;    // [8192, 512] f32
    (void)in_sizes; (void)n_in; (void)out_size;

    const size_t xf_elems = (size_t)B_ * T_ * H_;
    const bool pipelined = ws_size >= xf_elems * sizeof(float) + 64;

    // proj0: emb-gather GEMM -> xp0 in out cols 256..511
    proj_mfma<<<dim3(256), dim3(512), 0, stream>>>(
        emb, E_, 0, tokens, W_in0, b0, out, OW_, H_);

    if (pipelined) {
        float* xf = (float*)d_ws;
        unsigned int* flags = (unsigned int*)((float*)d_ws + xf_elems);
        // flags arrive poisoned (0xAA..) each launch; consumers' window check
        // treats poison as not-ready; producers overwrite with MAGIC+c.
        ltc_dual<<<dim3(16), dim3(512), 0, stream>>>(
            out, W_rec0, mask0, tau0, W_in1, b1, W_rec1, mask1, tau1, xf, flags);
    } else {
        ltc_single<<<dim3(8), dim3(512), 0, stream>>>(
            out, OW_, H_, out, 0, W_rec0, mask0, tau0);
        proj_mfma<<<dim3(256), dim3(512), 0, stream>>>(
            out, OW_, 0, nullptr, W_in1, b1, out, OW_, H_);
        ltc_single<<<dim3(8), dim3(512), 0, stream>>>(
            out, OW_, H_, out, H_, W_rec1, mask1, tau1);
    }
}